// Round 6
// baseline (557.847 us; speedup 1.0000x reference)
//
#include <hip/hip_runtime.h>
#include <math.h>

typedef unsigned short u16;
typedef __attribute__((ext_vector_type(8))) short short8;
typedef __attribute__((ext_vector_type(4))) float f32x4;

#define AS1C(p) ((const __attribute__((address_space(1))) void*)(p))
#define AS3(p)  ((__attribute__((address_space(3))) void*)(p))

static __device__ __forceinline__ float b2f(u16 h) {
    union { unsigned u; float f; } c; c.u = ((unsigned)h) << 16; return c.f;
}
static __device__ __forceinline__ u16 f2b(float f) {
    union { float f; unsigned u; } c; c.f = f;
    unsigned r = c.u + 0x7FFFu + ((c.u >> 16) & 1u);
    return (u16)(r >> 16);
}

// Epilogue modes (runtime)
#define EP_NONE     0
#define EP_RELU     1
#define EP_SIGMOID  2
#define EP_TANH_MUL 3   // out = tanh(acc+bias) * auxf[R,C]
#define EP_TANH_ADD 4   // out = auxf[R,C] + tanh(acc+bias)
#define EP_DIAG     5   // out = acc; if (R==C) += 0.9*tanh(auxf[R])

struct GDesc {
    const u16* A;       // [M, lda] bf16
    const u16* W;       // [N, K] bf16 dense
    const float* bias;  // [N] fp32 or null
    const float* auxf;  // fp32 aux (per-ep meaning) or null
    u16* outb;          // bf16 out, row stride ldd
    float* outf;        // fp32 out [M,N] dense, or null
    int lda, ldd, N, K, ep, nbm;
};

struct GArgs { GDesc d0, d1, d2; int s1, s2; };

// 256x256 tile, BK=64, 512 threads = 8 waves (2M x 4N), wave-out 128x64.
// LDS double-buffered (2 x (A 256x64 + B 256x64) = 128KB). Per iter:
// stage tile kt+1 into dbuf^1 (8 gload_lds, issued FIRST), then quadrant-
// pipelined compute on dbuf: reads for quadrant q+1 issued before MFMAs of
// quadrant q (separate reg sets AF0/AF1, BF reloaded once), then vmcnt(0)
// (cheap: loads had the whole iter) + one raw barrier.
// LDS 16B-slot swizzle (slot ^= row&7) on pre-swizzled GLOBAL source +
// swizzled ds_read (both sides; zero bank conflicts, R4/R5-proven).
__global__ __launch_bounds__(512, 2)
void gemm_q(GArgs ga)
{
    __shared__ __align__(16) u16 LDS[65536];   // buf d: A at d*32768, B at d*32768+16384

    const int bid = (int)blockIdx.x;
    GDesc dd = (bid < ga.s1) ? ga.d0 : ((bid < ga.s2) ? ga.d1 : ga.d2);
    const int b = bid - ((bid < ga.s1) ? 0 : ((bid < ga.s2) ? ga.s1 : ga.s2));

    const int tid  = threadIdx.x;       // 0..511
    const int lane = tid & 63;
    const int wid  = tid >> 6;          // 0..7
    const int wr   = wid >> 2;          // 0..1  (128-row half)
    const int wc   = wid & 3;           // 0..3  (64-col quarter)

    const int bm = b % dd.nbm;
    const int bn = b / dd.nbm;
    const int lda = dd.lda, K = dd.K, N = dd.N, ldd = dd.ldd;
    const int nkt = K >> 6;

    // staging: thread covers row (tid>>3) (+64 per sweep j), 16B slot (tid&7);
    // global source column pre-swizzled so swizzled ds_read sees natural data.
    const int srow  = tid >> 3;                       // 0..63
    const int sslot = tid & 7;
    const int sgcol = (sslot ^ (srow & 7)) * 8;       // u16 units
    const u16* Ag = dd.A + (size_t)(bm * 256 + srow) * lda + sgcol;
    const u16* Wg = dd.W + (size_t)(bn * 256 + srow) * K + sgcol;
    const int ldst = tid * 8;                         // linear LDS dest (u16)

    f32x4 acc[8][4];
#pragma unroll
    for (int m = 0; m < 8; ++m)
#pragma unroll
        for (int n = 0; n < 4; ++n) acc[m][n] = (f32x4){0.f, 0.f, 0.f, 0.f};

#define STAGE(bufi, kt)                                                          \
    {                                                                            \
        const int k0_ = (kt) << 6;                                               \
        u16* al_ = &LDS[(bufi) * 32768 + ldst];                                  \
        u16* bl_ = &LDS[(bufi) * 32768 + 16384 + ldst];                          \
        _Pragma("unroll")                                                        \
        for (int j = 0; j < 4; ++j)                                              \
            __builtin_amdgcn_global_load_lds(AS1C(Ag + (size_t)(j * 64) * lda + k0_), \
                                             AS3(al_ + j * 4096), 16, 0, 0);     \
        _Pragma("unroll")                                                        \
        for (int j = 0; j < 4; ++j)                                              \
            __builtin_amdgcn_global_load_lds(AS1C(Wg + (size_t)(j * 64) * K + k0_),   \
                                             AS3(bl_ + j * 4096), 16, 0, 0);     \
    }

    // fragment-read swizzle constants (frag row ≡ lane (mod 8))
    const int swz  = (lane & 7) << 4;           // byte XOR
    const int cnat = (lane >> 4) << 4;          // natural byte col base

    short8 AF0[4][2], AF1[4][2], BF[2][2];

#define LDA_SET(AF, mh, Al)                                                      \
    {                                                                            \
        const int rb_ = wr * 128 + (mh) * 64 + (lane & 15);                      \
        _Pragma("unroll")                                                        \
        for (int mm = 0; mm < 4; ++mm) {                                         \
            const u16* rp_ = (Al) + (rb_ + mm * 16) * 64;                        \
            _Pragma("unroll")                                                    \
            for (int ks = 0; ks < 2; ++ks)                                       \
                AF[mm][ks] = *(const short8*)(rp_ + ((((ks << 6) | cnat) ^ swz) >> 1)); \
        }                                                                        \
    }

#define LDB_SET(nh, Bl)                                                          \
    {                                                                            \
        const int rb_ = wc * 64 + (nh) * 32 + (lane & 15);                       \
        _Pragma("unroll")                                                        \
        for (int nn = 0; nn < 2; ++nn) {                                         \
            const u16* rp_ = (Bl) + (rb_ + nn * 16) * 64;                        \
            _Pragma("unroll")                                                    \
            for (int ks = 0; ks < 2; ++ks)                                       \
                BF[nn][ks] = *(const short8*)(rp_ + ((((ks << 6) | cnat) ^ swz) >> 1)); \
        }                                                                        \
    }

#define QMFMA(AF, mh, nh)                                                        \
    {                                                                            \
        __builtin_amdgcn_s_setprio(1);                                           \
        _Pragma("unroll")                                                        \
        for (int mm = 0; mm < 4; ++mm)                                           \
            _Pragma("unroll")                                                    \
            for (int nn = 0; nn < 2; ++nn)                                       \
                _Pragma("unroll")                                                \
                for (int ks = 0; ks < 2; ++ks)                                   \
                    acc[(mh) * 4 + mm][(nh) * 2 + nn] =                          \
                        __builtin_amdgcn_mfma_f32_16x16x32_bf16(                 \
                            AF[mm][ks], BF[nn][ks], acc[(mh) * 4 + mm][(nh) * 2 + nn], 0, 0, 0); \
        __builtin_amdgcn_s_setprio(0);                                           \
    }

    // prologue
    STAGE(0, 0);
    __builtin_amdgcn_sched_barrier(0);
    asm volatile("s_waitcnt vmcnt(0)" ::: "memory");
    __builtin_amdgcn_sched_barrier(0);
    __builtin_amdgcn_s_barrier();
    __builtin_amdgcn_sched_barrier(0);

    int buf = 0;
    for (int kt = 0; kt < nkt; ++kt) {
        const int ka = (kt + 1 < nkt) ? kt + 1 : nkt - 1;   // clamped (dead last iter)
        STAGE(buf ^ 1, ka);
        __builtin_amdgcn_sched_barrier(0);

        const u16* Al = &LDS[buf * 32768];
        const u16* Bl = Al + 16384;

        // quadrant-pipelined: reads run ahead of MFMAs (snake q00->q10->q11->q01)
        LDA_SET(AF0, 0, Al);
        LDB_SET(0, Bl);
        LDA_SET(AF1, 1, Al);
        QMFMA(AF0, 0, 0);          // lgkm allows AF1 reads outstanding
        QMFMA(AF1, 1, 0);
        LDB_SET(1, Bl);            // BF reload (WAR on regs, ordered by issue)
        QMFMA(AF1, 1, 1);
        QMFMA(AF0, 0, 1);

        __builtin_amdgcn_sched_barrier(0);
        asm volatile("s_waitcnt vmcnt(0)" ::: "memory");
        __builtin_amdgcn_sched_barrier(0);
        __builtin_amdgcn_s_barrier();
        __builtin_amdgcn_sched_barrier(0);
        buf ^= 1;
    }

#undef STAGE
#undef LDA_SET
#undef LDB_SET
#undef QMFMA

    // epilogue: D layout col=lane&15, row=(lane>>4)*4+j
    const int rbase = bm * 256 + wr * 128 + (lane >> 4) * 4;
    const int cbase = bn * 256 + wc * 64 + (lane & 15);
    const int ep = dd.ep;
#pragma unroll
    for (int n = 0; n < 4; ++n) {
        const int C = cbase + n * 16;
        const float bv = dd.bias ? dd.bias[C] : 0.f;
#pragma unroll
        for (int m = 0; m < 8; ++m) {
            const int R0 = rbase + m * 16;
#pragma unroll
            for (int j = 0; j < 4; ++j) {
                const int R = R0 + j;
                float v = acc[m][n][j] + bv;
                if (ep == EP_RELU)          v = fmaxf(v, 0.f);
                else if (ep == EP_SIGMOID)  v = 1.f / (1.f + expf(-v));
                else if (ep == EP_TANH_MUL) v = tanhf(v) * dd.auxf[(size_t)R * N + C];
                else if (ep == EP_TANH_ADD) v = dd.auxf[(size_t)R * N + C] + tanhf(v);
                else if (ep == EP_DIAG)     { if (R == C) v += 0.9f * tanhf(dd.auxf[R]); }
                dd.outb[(size_t)R * ldd + C] = f2b(v);
                if (dd.outf) dd.outf[(size_t)R * N + C] = v;
            }
        }
    }
}

// In-place LayerNorm over D=1024 bf16 (+optional ReLU). gam/bet fp32.
template<bool RELU>
__global__ __launch_bounds__(256)
void ln1024(u16* __restrict__ X, const float* __restrict__ gam, const float* __restrict__ bet)
{
    const int row = blockIdx.x;
    u16* xp = X + (size_t)row * 1024 + threadIdx.x * 4;
    u16 loc[4];
    *(uint2*)loc = *(const uint2*)xp;
    float x0 = b2f(loc[0]), x1 = b2f(loc[1]), x2 = b2f(loc[2]), x3 = b2f(loc[3]);
    float s = x0 + x1 + x2 + x3;
    float q = x0 * x0 + x1 * x1 + x2 * x2 + x3 * x3;
#pragma unroll
    for (int off = 32; off; off >>= 1) { s += __shfl_xor(s, off); q += __shfl_xor(q, off); }
    __shared__ float sm[8];
    const int wave = threadIdx.x >> 6, lane = threadIdx.x & 63;
    if (lane == 0) { sm[wave] = s; sm[4 + wave] = q; }
    __syncthreads();
    s = sm[0] + sm[1] + sm[2] + sm[3];
    q = sm[4] + sm[5] + sm[6] + sm[7];
    const float mean = s * (1.f / 1024.f);
    const float var  = q * (1.f / 1024.f) - mean * mean;
    const float inv  = rsqrtf(var + 1e-5f);
    const int cb = threadIdx.x * 4;
#pragma unroll
    for (int j = 0; j < 4; ++j) {
        float y = (b2f(loc[j]) - mean) * inv * gam[cb + j] + bet[cb + j];
        if (RELU) y = fmaxf(y, 0.f);
        loc[j] = f2b(y);
    }
    *(uint2*)xp = *(uint2*)loc;
}

// s_t = LN(s_prev + g*pm + (1-g)*wm) over D=1024. sp fp32, g/pm/wm bf16, out fp32.
__global__ __launch_bounds__(256)
void mix_ln(const float* __restrict__ sp, const u16* __restrict__ gt,
            const u16* __restrict__ pm, const u16* __restrict__ wm,
            const float* __restrict__ og, const float* __restrict__ ob,
            float* __restrict__ out)
{
    const int row = blockIdx.x;
    const size_t base = (size_t)row * 1024 + threadIdx.x * 4;
    float4 lsp = *(const float4*)(sp + base);
    u16 lg[4], lp[4], lw[4];
    *(uint2*)lg = *(const uint2*)(gt + base);
    *(uint2*)lp = *(const uint2*)(pm + base);
    *(uint2*)lw = *(const uint2*)(wm + base);
    float x[4];
    const float* lspp = (const float*)&lsp;
#pragma unroll
    for (int j = 0; j < 4; ++j) {
        float g = b2f(lg[j]);
        x[j] = lspp[j] + g * b2f(lp[j]) + (1.f - g) * b2f(lw[j]);
    }
    float s = x[0] + x[1] + x[2] + x[3];
    float q = x[0]*x[0] + x[1]*x[1] + x[2]*x[2] + x[3]*x[3];
#pragma unroll
    for (int off = 32; off; off >>= 1) { s += __shfl_xor(s, off); q += __shfl_xor(q, off); }
    __shared__ float sm[8];
    const int wave = threadIdx.x >> 6, lane = threadIdx.x & 63;
    if (lane == 0) { sm[wave] = s; sm[4 + wave] = q; }
    __syncthreads();
    s = sm[0] + sm[1] + sm[2] + sm[3];
    q = sm[4] + sm[5] + sm[6] + sm[7];
    const float mean = s * (1.f / 1024.f);
    const float var  = q * (1.f / 1024.f) - mean * mean;
    const float inv  = rsqrtf(var + 1e-5f);
    const int cb = threadIdx.x * 4;
    float4 o;
    float* op = (float*)&o;
#pragma unroll
    for (int j = 0; j < 4; ++j)
        op[j] = (x[j] - mean) * inv * og[cb + j] + ob[cb + j];
    *(float4*)(out + base) = o;
}

// Batched strided copy/convert: fp32->bf16 or bf16->bf16, 8 elems/thread.
struct CDesc { const void* src; u16* dst; int srcCols8; int dstStride; int dstOff; unsigned end; int isbf16; };
struct CArgs { CDesc d[16]; unsigned total; };

__global__ __launch_bounds__(256)
void multi_copy(CArgs ca)
{
    const unsigned idx = blockIdx.x * 256 + threadIdx.x;
    if (idx >= ca.total) return;
    int i = 0; unsigned start = 0;
    while (idx >= ca.d[i].end) { start = ca.d[i].end; ++i; }
    const CDesc cd = ca.d[i];
    const unsigned local = idx - start;
    const int r = local / cd.srcCols8;
    const int c = local % cd.srcCols8;
    u16 o[8];
    if (cd.isbf16) {
        *(uint4*)o = *(const uint4*)((const u16*)cd.src + ((size_t)r * cd.srcCols8 + c) * 8);
    } else {
        const float* s = (const float*)cd.src + ((size_t)r * cd.srcCols8 + c) * 8;
        const float4 a = *(const float4*)s;
        const float4 bq = *(const float4*)(s + 4);
        const float* ap = (const float*)&a;
        const float* bp = (const float*)&bq;
#pragma unroll
        for (int j = 0; j < 4; ++j) { o[j] = f2b(ap[j]); o[4 + j] = f2b(bp[j]); }
    }
    *(uint4*)(cd.dst + (size_t)r * cd.dstStride + cd.dstOff + (size_t)c * 8) = *(uint4*)o;
}

extern "C" void kernel_launch(void* const* d_in, const int* in_sizes, int n_in,
                              void* d_out, int out_size, void* d_ws, size_t ws_size,
                              hipStream_t stream)
{
    const float* s_prev = (const float*)d_in[0];
    const float* w_prev = (const float*)d_in[1];
    const float* p_prev = (const float*)d_in[2];
    const float* e_t    = (const float*)d_in[3];
    const float* c_t    = (const float*)d_in[4];
    const float* fw1    = (const float*)d_in[5];
    const float* fb1    = (const float*)d_in[6];
    const float* fln_g  = (const float*)d_in[7];
    const float* fln_b  = (const float*)d_in[8];
    const float* fw2    = (const float*)d_in[9];
    const float* fb2    = (const float*)d_in[10];
    const float* A_diag = (const float*)d_in[11];
    const float* A_U    = (const float*)d_in[12];
    const float* A_V    = (const float*)d_in[13];
    const float* amod_w = (const float*)d_in[14];
    const float* amod_b = (const float*)d_in[15];
    const float* bnet_w = (const float*)d_in[16];
    const float* bnet_b = (const float*)d_in[17];
    const float* pw1    = (const float*)d_in[18];
    const float* pb1    = (const float*)d_in[19];
    const float* pln_g  = (const float*)d_in[20];
    const float* pln_b  = (const float*)d_in[21];
    const float* pw2    = (const float*)d_in[22];
    const float* pb2    = (const float*)d_in[23];
    const float* pw3    = (const float*)d_in[24];
    const float* pb3    = (const float*)d_in[25];
    const float* gw     = (const float*)d_in[26];
    const float* gb     = (const float*)d_in[27];
    const float* uw     = (const float*)d_in[28];
    const float* up     = (const float*)d_in[29];
    const float* oln_g  = (const float*)d_in[30];
    const float* oln_b  = (const float*)d_in[31];

    float* out_s = (float*)d_out;                    // [8192,1024]
    float* out_w = out_s + (size_t)8192 * 1024;      // [8192,1024]
    float* out_p = out_w + (size_t)8192 * 1024;      // [8192,512]

    u16* ws = (u16*)d_ws;
    u16* FIN  = ws;                    // [8192,2560]; later PIN [8192,1536] at base
    u16* W_bf = ws + 12582912;         // [8192,1024]
    u16* H    = ws + 20971520;         // [8192,1024]; later P_bf [8192,512]
    u16* P_bf = H;
    u16* Z    = ws + 29360128;         // [8192,512]
    u16* G    = ws + 33554432;         // [8192,1024]
    u16* ACAT = ws + 41943040;         // [8192,2048]; later PM/WM
    u16* PM   = ACAT;
    u16* WM   = ACAT + 8388608;
    u16* WCAT = ws + 58720256;         // [1024,2048]
    u16* wb   = ws + 60817408;         // bf16 weights pool
    u16* fw1b  = wb;
    u16* gwb   = wb + 2621440;
    u16* fw2b  = wb + 5242880;
    u16* amodb = wb + 5767168;
    u16* pw1b  = wb + 6291456;
    u16* pw2b  = wb + 7864320;
    u16* pw3b  = wb + 8388608;
    u16* uwb   = wb + 8650752;
    u16* upb   = wb + 9699328;
    u16* AUb   = wb + 10223616;
    u16* AVb   = wb + 10485760;        // pool ends ws+10,747,904

    const dim3 blk(256);
    const dim3 blk512(512);

    // ---------- batch 1: weight cvts + FIN assembly + c_t->ACAT + bnet_w->WCAT
    {
        CArgs ca; unsigned cum = 0; int nd = 0;
        auto push = [&](const void* src, u16* dst, int cols8, int stride, int off,
                        int rows, int isbf) {
            cum += (unsigned)rows * cols8;
            ca.d[nd++] = CDesc{src, dst, cols8, stride, off, cum, isbf};
        };
        push(fw1,    fw1b,  320, 2560, 0,    1024, 0);
        push(gw,     gwb,   320, 2560, 0,    1024, 0);
        push(fw2,    fw2b,  128, 1024, 0,    512,  0);
        push(amod_w, amodb, 64,  512,  0,    1024, 0);
        push(pw1,    pw1b,  192, 1536, 0,    1024, 0);
        push(pw2,    pw2b,  128, 1024, 0,    512,  0);
        push(pw3,    pw3b,  64,  512,  0,    512,  0);
        push(uw,     uwb,   128, 1024, 0,    1024, 0);
        push(up,     upb,   64,  512,  0,    1024, 0);
        push(A_U,    AUb,   32,  256,  0,    1024, 0);
        push(A_V,    AVb,   32,  256,  0,    1024, 0);
        push(s_prev, FIN,   128, 2560, 0,    8192, 0);
        push(e_t,    FIN,   128, 2560, 1024, 8192, 0);
        push(c_t,    FIN,   64,  2560, 2048, 8192, 0);
        push(c_t,    ACAT,  64,  2048, 1024, 8192, 0);
        push(bnet_w, WCAT,  128, 2048, 1024, 1024, 0);
        ca.total = cum;
        multi_copy<<<dim3((cum + 255) / 256), blk, 0, stream>>>(ca);
    }

    // ---------- fused GEMM 1: fw1 (H) || gate (G) -> 256 blocks
    {
        GArgs ga;
        ga.d0 = GDesc{FIN, fw1b, fb1, nullptr, H, nullptr, 2560, 1024, 1024, 2560, EP_NONE,    32};
        ga.d1 = GDesc{FIN, gwb,  gb,  nullptr, G, nullptr, 2560, 1024, 1024, 2560, EP_SIGMOID, 32};
        ga.d2 = ga.d1; ga.s1 = 128; ga.s2 = 256;
        gemm_q<<<dim3(256), blk512, 0, stream>>>(ga);
    }
    ln1024<true><<<8192, blk, 0, stream>>>(H, fln_g, fln_b);

    // ---------- fused GEMM 2: fw2 (Z) || amod (ACAT) || A_base (WCAT) -> 208 blocks
    {
        GArgs ga;
        ga.d0 = GDesc{H,          fw2b,  fb2,     nullptr, Z,    nullptr, 1024, 512,  512,  1024, EP_NONE,     32};
        ga.d1 = GDesc{FIN + 2048, amodb, amod_b,  w_prev,  ACAT, nullptr, 2560, 2048, 1024, 512,  EP_TANH_MUL, 32};
        ga.d2 = GDesc{AUb,        AVb,   nullptr, A_diag,  WCAT, nullptr, 256,  2048, 1024, 256,  EP_DIAG,     4};
        ga.s1 = 64; ga.s2 = 192;
        gemm_q<<<dim3(208), blk512, 0, stream>>>(ga);
    }

    // ---------- batch 2: PIN = [p_prev || z || c_t] at FIN base; Z -> ACAT col 1536
    {
        CArgs ca; unsigned cum = 0; int nd = 0;
        auto push = [&](const void* src, u16* dst, int cols8, int stride, int off,
                        int rows, int isbf) {
            cum += (unsigned)rows * cols8;
            ca.d[nd++] = CDesc{src, dst, cols8, stride, off, cum, isbf};
        };
        push(p_prev, FIN,  64, 1536, 0,    8192, 0);
        push(Z,      FIN,  64, 1536, 512,  8192, 1);
        push(c_t,    FIN,  64, 1536, 1024, 8192, 0);
        push(Z,      ACAT, 64, 2048, 1536, 8192, 1);
        ca.total = cum;
        multi_copy<<<dim3((cum + 255) / 256), blk, 0, stream>>>(ca);
    }

    // ---------- fused GEMM 3: w_t (ACAT@WCAT^T) || pw1 (PIN) -> 256 blocks
    {
        GArgs ga;
        ga.d0 = GDesc{ACAT, WCAT, bnet_b, nullptr, W_bf, out_w,   2048, 1024, 1024, 2048, EP_NONE, 32};
        ga.d1 = GDesc{FIN,  pw1b, pb1,    nullptr, H,    nullptr, 1536, 1024, 1024, 1536, EP_NONE, 32};
        ga.d2 = ga.d1; ga.s1 = 128; ga.s2 = 256;
        gemm_q<<<dim3(256), blk512, 0, stream>>>(ga);
    }
    ln1024<true><<<8192, blk, 0, stream>>>(H, pln_g, pln_b);

    // ---------- fused GEMM 4: pw2 (H -> Z, relu) || uw (W_bf -> WM) -> 192 blocks
    {
        GArgs ga;
        ga.d0 = GDesc{H,    pw2b, pb2,     nullptr, Z,  nullptr, 1024, 512,  512,  1024, EP_RELU, 32};
        ga.d1 = GDesc{W_bf, uwb,  nullptr, nullptr, WM, nullptr, 1024, 1024, 1024, 1024, EP_NONE, 32};
        ga.d2 = ga.d1; ga.s1 = 64; ga.s2 = 192;
        gemm_q<<<dim3(192), blk512, 0, stream>>>(ga);
    }

    // ---------- pw3: p_t = p_prev + tanh(Z@pw3^T + pb3) -> P_bf + out_p
    {
        GArgs ga;
        ga.d0 = GDesc{Z, pw3b, pb3, p_prev, P_bf, out_p, 512, 512, 512, 512, EP_TANH_ADD, 32};
        ga.d1 = ga.d0; ga.d2 = ga.d0; ga.s1 = 64; ga.s2 = 64;
        gemm_q<<<dim3(64), blk512, 0, stream>>>(ga);
    }

    // ---------- up: pm = P_bf @ up^T -> PM
    {
        GArgs ga;
        ga.d0 = GDesc{P_bf, upb, nullptr, nullptr, PM, nullptr, 512, 1024, 1024, 512, EP_NONE, 32};
        ga.d1 = ga.d0; ga.d2 = ga.d0; ga.s1 = 128; ga.s2 = 128;
        gemm_q<<<dim3(128), blk512, 0, stream>>>(ga);
    }

    mix_ln<<<8192, blk, 0, stream>>>(s_prev, G, PM, WM, oln_g, oln_b, out_s);
}

// Round 7
// 529.522 us; speedup vs baseline: 1.0535x; 1.0535x over previous
//
#include <hip/hip_runtime.h>
#include <math.h>

typedef unsigned short u16;
typedef __attribute__((ext_vector_type(8))) short short8;
typedef __attribute__((ext_vector_type(4))) float f32x4;

#define AS1C(p) ((const __attribute__((address_space(1))) void*)(p))
#define AS3(p)  ((__attribute__((address_space(3))) void*)(p))

static __device__ __forceinline__ float b2f(u16 h) {
    union { unsigned u; float f; } c; c.u = ((unsigned)h) << 16; return c.f;
}
static __device__ __forceinline__ u16 f2b(float f) {
    union { float f; unsigned u; } c; c.f = f;
    unsigned r = c.u + 0x7FFFu + ((c.u >> 16) & 1u);
    return (u16)(r >> 16);
}

// Epilogue modes (runtime)
#define EP_NONE     0
#define EP_RELU     1
#define EP_SIGMOID  2
#define EP_TANH_MUL 3   // out = tanh(acc+bias) * auxf[R,C]
#define EP_TANH_ADD 4   // out = auxf[R,C] + tanh(acc+bias)
#define EP_DIAG     5   // out = acc; if (R==C) += 0.9*tanh(auxf[R])

struct GDesc {
    const u16* A;       // [M, lda] bf16
    const u16* W;       // [N, K] bf16 dense
    const float* bias;  // [N] fp32 or null
    const float* auxf;  // fp32 aux (per-ep meaning) or null
    u16* outb;          // bf16 out, row stride ldd
    float* outf;        // fp32 out [M,N] dense, or null
    int lda, ldd, N, K, ep, nbm;
};

struct GArgs { GDesc d0, d1, d2; int s1, s2; };

// 256x256 tile, BK=64, 512 threads = 8 waves. 4-phase-per-K-tile pipeline:
// quadrant (mh,nh) of the BLOCK tile: rows [mh*128,+128) x cols [nh*128,+128);
// wave (wr,wc) owns rows {mh*128+wr*64..+64} and cols {nh*128+wc*32..+32} of
// each quadrant. Phase p computes one quadrant (16 MFMA/wave) and stages one
// half-tile of K-tile t+1 (2 gload_lds/thread). Counted vmcnt(4) + barrier at
// phases 1-3 lands exactly the half-tiles first consumed that phase; 2
// half-tiles always stay in flight (never vmcnt 0). LDS 16B-slot swizzle
// (slot ^= row&7) on pre-swizzled global source + swizzled ds_read (zero
// bank conflicts, R4-R6 proven). REQUIRES K%64==0, K>=256.
__global__ __launch_bounds__(512, 2)
void gemm_8p(GArgs ga)
{
    __shared__ __align__(16) u16 LDS[65536];   // buf d: A at d*32768, B at d*32768+16384

    const int bid = (int)blockIdx.x;
    GDesc dd = (bid < ga.s1) ? ga.d0 : ((bid < ga.s2) ? ga.d1 : ga.d2);
    const int b = bid - ((bid < ga.s1) ? 0 : ((bid < ga.s2) ? ga.s1 : ga.s2));

    const int tid  = threadIdx.x;       // 0..511
    const int lane = tid & 63;
    const int wid  = tid >> 6;          // 0..7
    const int wr   = wid >> 2;          // 0..1  (64-row strip within quadrant)
    const int wc   = wid & 3;           // 0..3  (32-col strip within quadrant)

    const int bm = b % dd.nbm;
    const int bn = b / dd.nbm;
    const int lda = dd.lda, K = dd.K, N = dd.N, ldd = dd.ldd;
    const int nkt = K >> 6;

    // staging: thread covers row (tid>>3) (+64 per sweep j), 16B slot (tid&7);
    // global source column pre-swizzled so swizzled ds_read sees natural data.
    const int srow  = tid >> 3;                       // 0..63
    const int sslot = tid & 7;
    const int sgcol = (sslot ^ (srow & 7)) * 8;       // u16 units
    const u16* Ag = dd.A + (size_t)(bm * 256 + srow) * lda + sgcol;
    const u16* Wg = dd.W + (size_t)(bn * 256 + srow) * K + sgcol;
    const int ldst = tid * 8;                         // linear LDS dest (u16)

    f32x4 acc[8][4];
#pragma unroll
    for (int m = 0; m < 8; ++m)
#pragma unroll
        for (int n = 0; n < 4; ++n) acc[m][n] = (f32x4){0.f, 0.f, 0.f, 0.f};

    // A-half h = block rows [h*128,+128) = sweeps {2h, 2h+1}; B-half likewise.
#define STAGE_AH(bufi, kt, h)                                                    \
    {                                                                            \
        const int k0_ = (kt) << 6;                                               \
        u16* d_ = &LDS[(bufi) * 32768 + ldst];                                   \
        _Pragma("unroll")                                                        \
        for (int j = 2 * (h); j < 2 * (h) + 2; ++j)                              \
            __builtin_amdgcn_global_load_lds(AS1C(Ag + (size_t)(j * 64) * lda + k0_), \
                                             AS3(d_ + j * 4096), 16, 0, 0);      \
    }
#define STAGE_BH(bufi, kt, h)                                                    \
    {                                                                            \
        const int k0_ = (kt) << 6;                                               \
        u16* d_ = &LDS[(bufi) * 32768 + 16384 + ldst];                           \
        _Pragma("unroll")                                                        \
        for (int j = 2 * (h); j < 2 * (h) + 2; ++j)                              \
            __builtin_amdgcn_global_load_lds(AS1C(Wg + (size_t)(j * 64) * K + k0_),   \
                                             AS3(d_ + j * 4096), 16, 0, 0);      \
    }

    // counted wait + barrier (collective landing guarantee: per-thread vmcnt
    // then barrier => staged data visible to ALL threads)
#define VWAIT4()                                                                 \
    {                                                                            \
        __builtin_amdgcn_sched_barrier(0);                                       \
        asm volatile("s_waitcnt vmcnt(4)" ::: "memory");                         \
        __builtin_amdgcn_sched_barrier(0);                                       \
        __builtin_amdgcn_s_barrier();                                            \
        __builtin_amdgcn_sched_barrier(0);                                       \
    }

    // fragment-read swizzle constants (frag row ≡ lane (mod 8))
    const int swz  = (lane & 7) << 4;           // byte XOR
    const int cnat = (lane >> 4) << 4;          // natural byte col base

    short8 AF0[4][2], AF1[4][2], BF[2][2];

#define LDA_SET(AF, mh, Al)                                                      \
    {                                                                            \
        const int rb_ = (mh) * 128 + wr * 64 + (lane & 15);                      \
        _Pragma("unroll")                                                        \
        for (int mm = 0; mm < 4; ++mm) {                                         \
            const u16* rp_ = (Al) + (rb_ + mm * 16) * 64;                        \
            _Pragma("unroll")                                                    \
            for (int ks = 0; ks < 2; ++ks)                                       \
                AF[mm][ks] = *(const short8*)(rp_ + ((((ks << 6) | cnat) ^ swz) >> 1)); \
        }                                                                        \
    }
#define LDB_SET(nh, Bl)                                                          \
    {                                                                            \
        const int rb_ = (nh) * 128 + wc * 32 + (lane & 15);                      \
        _Pragma("unroll")                                                        \
        for (int nn = 0; nn < 2; ++nn) {                                         \
            const u16* rp_ = (Bl) + (rb_ + nn * 16) * 64;                        \
            _Pragma("unroll")                                                    \
            for (int ks = 0; ks < 2; ++ks)                                       \
                BF[nn][ks] = *(const short8*)(rp_ + ((((ks << 6) | cnat) ^ swz) >> 1)); \
        }                                                                        \
    }
#define QMFMA(AF, mh, nh)                                                        \
    {                                                                            \
        __builtin_amdgcn_s_setprio(1);                                           \
        _Pragma("unroll")                                                        \
        for (int mm = 0; mm < 4; ++mm)                                           \
            _Pragma("unroll")                                                    \
            for (int nn = 0; nn < 2; ++nn)                                       \
                _Pragma("unroll")                                                \
                for (int ks = 0; ks < 2; ++ks)                                   \
                    acc[(mh) * 4 + mm][(nh) * 2 + nn] =                          \
                        __builtin_amdgcn_mfma_f32_16x16x32_bf16(                 \
                            AF[mm][ks], BF[nn][ks], acc[(mh) * 4 + mm][(nh) * 2 + nn], 0, 0, 0); \
        __builtin_amdgcn_s_setprio(0);                                           \
    }

    // ---- prologue: stage all 4 half-tiles of tile 0 (8 loads, issue order
    // matches steady-state: A0, B0, A1, B1)
    STAGE_AH(0, 0, 0);
    STAGE_BH(0, 0, 0);
    STAGE_AH(0, 0, 1);
    STAGE_BH(0, 0, 1);

    int buf = 0;
    for (int kt = 0; kt < nkt; ++kt) {
        const int ka = (kt + 1 < nkt) ? kt + 1 : nkt - 1;   // clamped (dead last iter)
        const u16* Al = &LDS[buf * 32768];
        const u16* Bl = Al + 16384;
        const int nb = buf ^ 1;

        // ---- phase 1: needs A0(t), B0(t)  [the 2 oldest staged half-tiles]
        VWAIT4();
        LDA_SET(AF0, 0, Al);
        LDB_SET(0, Bl);
        STAGE_AH(nb, ka, 0);
        QMFMA(AF0, 0, 0);

        // ---- phase 2: needs A1(t)
        VWAIT4();
        LDA_SET(AF1, 1, Al);
        STAGE_BH(nb, ka, 0);
        QMFMA(AF1, 1, 0);

        // ---- phase 3: needs B1(t)
        VWAIT4();
        LDB_SET(1, Bl);
        STAGE_AH(nb, ka, 1);
        QMFMA(AF1, 1, 1);

        // ---- phase 4: all data already landed; no wait, no barrier
        __builtin_amdgcn_sched_barrier(0);
        STAGE_BH(nb, ka, 1);
        QMFMA(AF0, 0, 1);

        buf ^= 1;
    }

#undef STAGE_AH
#undef STAGE_BH
#undef VWAIT4
#undef LDA_SET
#undef LDB_SET
#undef QMFMA

    // epilogue: frag (m,n): R = (m>>2)*128 + wr*64 + (m&3)*16 + (lane>>4)*4 + j
    //                       C = (n>>1)*128 + wc*32 + (n&1)*16 + (lane&15)
    const int ep = dd.ep;
#pragma unroll
    for (int n = 0; n < 4; ++n) {
        const int C = bn * 256 + (n >> 1) * 128 + wc * 32 + (n & 1) * 16 + (lane & 15);
        const float bv = dd.bias ? dd.bias[C] : 0.f;
#pragma unroll
        for (int m = 0; m < 8; ++m) {
            const int R0 = bm * 256 + (m >> 2) * 128 + wr * 64 + (m & 3) * 16 + ((lane >> 4) << 2);
#pragma unroll
            for (int j = 0; j < 4; ++j) {
                const int R = R0 + j;
                float v = acc[m][n][j] + bv;
                if (ep == EP_RELU)          v = fmaxf(v, 0.f);
                else if (ep == EP_SIGMOID)  v = 1.f / (1.f + expf(-v));
                else if (ep == EP_TANH_MUL) v = tanhf(v) * dd.auxf[(size_t)R * N + C];
                else if (ep == EP_TANH_ADD) v = dd.auxf[(size_t)R * N + C] + tanhf(v);
                else if (ep == EP_DIAG)     { if (R == C) v += 0.9f * tanhf(dd.auxf[R]); }
                dd.outb[(size_t)R * ldd + C] = f2b(v);
                if (dd.outf) dd.outf[(size_t)R * N + C] = v;
            }
        }
    }
}

// In-place LayerNorm over D=1024 bf16 (+optional ReLU). gam/bet fp32.
template<bool RELU>
__global__ __launch_bounds__(256)
void ln1024(u16* __restrict__ X, const float* __restrict__ gam, const float* __restrict__ bet)
{
    const int row = blockIdx.x;
    u16* xp = X + (size_t)row * 1024 + threadIdx.x * 4;
    u16 loc[4];
    *(uint2*)loc = *(const uint2*)xp;
    float x0 = b2f(loc[0]), x1 = b2f(loc[1]), x2 = b2f(loc[2]), x3 = b2f(loc[3]);
    float s = x0 + x1 + x2 + x3;
    float q = x0 * x0 + x1 * x1 + x2 * x2 + x3 * x3;
#pragma unroll
    for (int off = 32; off; off >>= 1) { s += __shfl_xor(s, off); q += __shfl_xor(q, off); }
    __shared__ float sm[8];
    const int wave = threadIdx.x >> 6, lane = threadIdx.x & 63;
    if (lane == 0) { sm[wave] = s; sm[4 + wave] = q; }
    __syncthreads();
    s = sm[0] + sm[1] + sm[2] + sm[3];
    q = sm[4] + sm[5] + sm[6] + sm[7];
    const float mean = s * (1.f / 1024.f);
    const float var  = q * (1.f / 1024.f) - mean * mean;
    const float inv  = rsqrtf(var + 1e-5f);
    const int cb = threadIdx.x * 4;
#pragma unroll
    for (int j = 0; j < 4; ++j) {
        float y = (b2f(loc[j]) - mean) * inv * gam[cb + j] + bet[cb + j];
        if (RELU) y = fmaxf(y, 0.f);
        loc[j] = f2b(y);
    }
    *(uint2*)xp = *(uint2*)loc;
}

// s_t = LN(s_prev + g*pm + (1-g)*wm) over D=1024. sp fp32, g/pm/wm bf16, out fp32.
__global__ __launch_bounds__(256)
void mix_ln(const float* __restrict__ sp, const u16* __restrict__ gt,
            const u16* __restrict__ pm, const u16* __restrict__ wm,
            const float* __restrict__ og, const float* __restrict__ ob,
            float* __restrict__ out)
{
    const int row = blockIdx.x;
    const size_t base = (size_t)row * 1024 + threadIdx.x * 4;
    float4 lsp = *(const float4*)(sp + base);
    u16 lg[4], lp[4], lw[4];
    *(uint2*)lg = *(const uint2*)(gt + base);
    *(uint2*)lp = *(const uint2*)(pm + base);
    *(uint2*)lw = *(const uint2*)(wm + base);
    float x[4];
    const float* lspp = (const float*)&lsp;
#pragma unroll
    for (int j = 0; j < 4; ++j) {
        float g = b2f(lg[j]);
        x[j] = lspp[j] + g * b2f(lp[j]) + (1.f - g) * b2f(lw[j]);
    }
    float s = x[0] + x[1] + x[2] + x[3];
    float q = x[0]*x[0] + x[1]*x[1] + x[2]*x[2] + x[3]*x[3];
#pragma unroll
    for (int off = 32; off; off >>= 1) { s += __shfl_xor(s, off); q += __shfl_xor(q, off); }
    __shared__ float sm[8];
    const int wave = threadIdx.x >> 6, lane = threadIdx.x & 63;
    if (lane == 0) { sm[wave] = s; sm[4 + wave] = q; }
    __syncthreads();
    s = sm[0] + sm[1] + sm[2] + sm[3];
    q = sm[4] + sm[5] + sm[6] + sm[7];
    const float mean = s * (1.f / 1024.f);
    const float var  = q * (1.f / 1024.f) - mean * mean;
    const float inv  = rsqrtf(var + 1e-5f);
    const int cb = threadIdx.x * 4;
    float4 o;
    float* op = (float*)&o;
#pragma unroll
    for (int j = 0; j < 4; ++j)
        op[j] = (x[j] - mean) * inv * og[cb + j] + ob[cb + j];
    *(float4*)(out + base) = o;
}

// Batched strided copy/convert: fp32->bf16 or bf16->bf16, 8 elems/thread.
struct CDesc { const void* src; u16* dst; int srcCols8; int dstStride; int dstOff; unsigned end; int isbf16; };
struct CArgs { CDesc d[16]; unsigned total; };

__global__ __launch_bounds__(256)
void multi_copy(CArgs ca)
{
    const unsigned idx = blockIdx.x * 256 + threadIdx.x;
    if (idx >= ca.total) return;
    int i = 0; unsigned start = 0;
    while (idx >= ca.d[i].end) { start = ca.d[i].end; ++i; }
    const CDesc cd = ca.d[i];
    const unsigned local = idx - start;
    const int r = local / cd.srcCols8;
    const int c = local % cd.srcCols8;
    u16 o[8];
    if (cd.isbf16) {
        *(uint4*)o = *(const uint4*)((const u16*)cd.src + ((size_t)r * cd.srcCols8 + c) * 8);
    } else {
        const float* s = (const float*)cd.src + ((size_t)r * cd.srcCols8 + c) * 8;
        const float4 a = *(const float4*)s;
        const float4 bq = *(const float4*)(s + 4);
        const float* ap = (const float*)&a;
        const float* bp = (const float*)&bq;
#pragma unroll
        for (int j = 0; j < 4; ++j) { o[j] = f2b(ap[j]); o[4 + j] = f2b(bp[j]); }
    }
    *(uint4*)(cd.dst + (size_t)r * cd.dstStride + cd.dstOff + (size_t)c * 8) = *(uint4*)o;
}

extern "C" void kernel_launch(void* const* d_in, const int* in_sizes, int n_in,
                              void* d_out, int out_size, void* d_ws, size_t ws_size,
                              hipStream_t stream)
{
    const float* s_prev = (const float*)d_in[0];
    const float* w_prev = (const float*)d_in[1];
    const float* p_prev = (const float*)d_in[2];
    const float* e_t    = (const float*)d_in[3];
    const float* c_t    = (const float*)d_in[4];
    const float* fw1    = (const float*)d_in[5];
    const float* fb1    = (const float*)d_in[6];
    const float* fln_g  = (const float*)d_in[7];
    const float* fln_b  = (const float*)d_in[8];
    const float* fw2    = (const float*)d_in[9];
    const float* fb2    = (const float*)d_in[10];
    const float* A_diag = (const float*)d_in[11];
    const float* A_U    = (const float*)d_in[12];
    const float* A_V    = (const float*)d_in[13];
    const float* amod_w = (const float*)d_in[14];
    const float* amod_b = (const float*)d_in[15];
    const float* bnet_w = (const float*)d_in[16];
    const float* bnet_b = (const float*)d_in[17];
    const float* pw1    = (const float*)d_in[18];
    const float* pb1    = (const float*)d_in[19];
    const float* pln_g  = (const float*)d_in[20];
    const float* pln_b  = (const float*)d_in[21];
    const float* pw2    = (const float*)d_in[22];
    const float* pb2    = (const float*)d_in[23];
    const float* pw3    = (const float*)d_in[24];
    const float* pb3    = (const float*)d_in[25];
    const float* gw     = (const float*)d_in[26];
    const float* gb     = (const float*)d_in[27];
    const float* uw     = (const float*)d_in[28];
    const float* up     = (const float*)d_in[29];
    const float* oln_g  = (const float*)d_in[30];
    const float* oln_b  = (const float*)d_in[31];

    float* out_s = (float*)d_out;                    // [8192,1024]
    float* out_w = out_s + (size_t)8192 * 1024;      // [8192,1024]
    float* out_p = out_w + (size_t)8192 * 1024;      // [8192,512]

    u16* ws = (u16*)d_ws;
    u16* FIN  = ws;                    // [8192,2560]; later PIN [8192,1536] at base
    u16* W_bf = ws + 12582912;         // [8192,1024]
    u16* H    = ws + 20971520;         // [8192,1024]; later P_bf [8192,512]
    u16* P_bf = H;
    u16* Z    = ws + 29360128;         // [8192,512]
    u16* G    = ws + 33554432;         // [8192,1024]
    u16* ACAT = ws + 41943040;         // [8192,2048]; later PM/WM
    u16* PM   = ACAT;
    u16* WM   = ACAT + 8388608;
    u16* WCAT = ws + 58720256;         // [1024,2048]
    u16* wb   = ws + 60817408;         // bf16 weights pool
    u16* fw1b  = wb;
    u16* gwb   = wb + 2621440;
    u16* fw2b  = wb + 5242880;
    u16* amodb = wb + 5767168;
    u16* pw1b  = wb + 6291456;
    u16* pw2b  = wb + 7864320;
    u16* pw3b  = wb + 8388608;
    u16* uwb   = wb + 8650752;
    u16* upb   = wb + 9699328;
    u16* AUb   = wb + 10223616;
    u16* AVb   = wb + 10485760;        // pool ends ws+10,747,904

    const dim3 blk(256);
    const dim3 blk512(512);

    // ---------- batch 1: weight cvts + FIN assembly + c_t->ACAT + bnet_w->WCAT
    {
        CArgs ca; unsigned cum = 0; int nd = 0;
        auto push = [&](const void* src, u16* dst, int cols8, int stride, int off,
                        int rows, int isbf) {
            cum += (unsigned)rows * cols8;
            ca.d[nd++] = CDesc{src, dst, cols8, stride, off, cum, isbf};
        };
        push(fw1,    fw1b,  320, 2560, 0,    1024, 0);
        push(gw,     gwb,   320, 2560, 0,    1024, 0);
        push(fw2,    fw2b,  128, 1024, 0,    512,  0);
        push(amod_w, amodb, 64,  512,  0,    1024, 0);
        push(pw1,    pw1b,  192, 1536, 0,    1024, 0);
        push(pw2,    pw2b,  128, 1024, 0,    512,  0);
        push(pw3,    pw3b,  64,  512,  0,    512,  0);
        push(uw,     uwb,   128, 1024, 0,    1024, 0);
        push(up,     upb,   64,  512,  0,    1024, 0);
        push(A_U,    AUb,   32,  256,  0,    1024, 0);
        push(A_V,    AVb,   32,  256,  0,    1024, 0);
        push(s_prev, FIN,   128, 2560, 0,    8192, 0);
        push(e_t,    FIN,   128, 2560, 1024, 8192, 0);
        push(c_t,    FIN,   64,  2560, 2048, 8192, 0);
        push(c_t,    ACAT,  64,  2048, 1024, 8192, 0);
        push(bnet_w, WCAT,  128, 2048, 1024, 1024, 0);
        ca.total = cum;
        multi_copy<<<dim3((cum + 255) / 256), blk, 0, stream>>>(ca);
    }

    // ---------- fused GEMM 1: fw1 (H) || gate (G) -> 256 blocks
    {
        GArgs ga;
        ga.d0 = GDesc{FIN, fw1b, fb1, nullptr, H, nullptr, 2560, 1024, 1024, 2560, EP_NONE,    32};
        ga.d1 = GDesc{FIN, gwb,  gb,  nullptr, G, nullptr, 2560, 1024, 1024, 2560, EP_SIGMOID, 32};
        ga.d2 = ga.d1; ga.s1 = 128; ga.s2 = 256;
        gemm_8p<<<dim3(256), blk512, 0, stream>>>(ga);
    }
    ln1024<true><<<8192, blk, 0, stream>>>(H, fln_g, fln_b);

    // ---------- fused GEMM 2: fw2 (Z) || amod (ACAT) || A_base (WCAT) -> 208 blocks
    {
        GArgs ga;
        ga.d0 = GDesc{H,          fw2b,  fb2,     nullptr, Z,    nullptr, 1024, 512,  512,  1024, EP_NONE,     32};
        ga.d1 = GDesc{FIN + 2048, amodb, amod_b,  w_prev,  ACAT, nullptr, 2560, 2048, 1024, 512,  EP_TANH_MUL, 32};
        ga.d2 = GDesc{AUb,        AVb,   nullptr, A_diag,  WCAT, nullptr, 256,  2048, 1024, 256,  EP_DIAG,     4};
        ga.s1 = 64; ga.s2 = 192;
        gemm_8p<<<dim3(208), blk512, 0, stream>>>(ga);
    }

    // ---------- batch 2: PIN = [p_prev || z || c_t] at FIN base; Z -> ACAT col 1536
    {
        CArgs ca; unsigned cum = 0; int nd = 0;
        auto push = [&](const void* src, u16* dst, int cols8, int stride, int off,
                        int rows, int isbf) {
            cum += (unsigned)rows * cols8;
            ca.d[nd++] = CDesc{src, dst, cols8, stride, off, cum, isbf};
        };
        push(p_prev, FIN,  64, 1536, 0,    8192, 0);
        push(Z,      FIN,  64, 1536, 512,  8192, 1);
        push(c_t,    FIN,  64, 1536, 1024, 8192, 0);
        push(Z,      ACAT, 64, 2048, 1536, 8192, 1);
        ca.total = cum;
        multi_copy<<<dim3((cum + 255) / 256), blk, 0, stream>>>(ca);
    }

    // ---------- fused GEMM 3: w_t (ACAT@WCAT^T) || pw1 (PIN) -> 256 blocks
    {
        GArgs ga;
        ga.d0 = GDesc{ACAT, WCAT, bnet_b, nullptr, W_bf, out_w,   2048, 1024, 1024, 2048, EP_NONE, 32};
        ga.d1 = GDesc{FIN,  pw1b, pb1,    nullptr, H,    nullptr, 1536, 1024, 1024, 1536, EP_NONE, 32};
        ga.d2 = ga.d1; ga.s1 = 128; ga.s2 = 256;
        gemm_8p<<<dim3(256), blk512, 0, stream>>>(ga);
    }
    ln1024<true><<<8192, blk, 0, stream>>>(H, pln_g, pln_b);

    // ---------- fused GEMM 4: pw2 (H -> Z, relu) || uw (W_bf -> WM) -> 192 blocks
    {
        GArgs ga;
        ga.d0 = GDesc{H,    pw2b, pb2,     nullptr, Z,  nullptr, 1024, 512,  512,  1024, EP_RELU, 32};
        ga.d1 = GDesc{W_bf, uwb,  nullptr, nullptr, WM, nullptr, 1024, 1024, 1024, 1024, EP_NONE, 32};
        ga.d2 = ga.d1; ga.s1 = 64; ga.s2 = 192;
        gemm_8p<<<dim3(192), blk512, 0, stream>>>(ga);
    }

    // ---------- pw3: p_t = p_prev + tanh(Z@pw3^T + pb3) -> P_bf + out_p
    {
        GArgs ga;
        ga.d0 = GDesc{Z, pw3b, pb3, p_prev, P_bf, out_p, 512, 512, 512, 512, EP_TANH_ADD, 32};
        ga.d1 = ga.d0; ga.d2 = ga.d0; ga.s1 = 64; ga.s2 = 64;
        gemm_8p<<<dim3(64), blk512, 0, stream>>>(ga);
    }

    // ---------- up: pm = P_bf @ up^T -> PM
    {
        GArgs ga;
        ga.d0 = GDesc{P_bf, upb, nullptr, nullptr, PM, nullptr, 512, 1024, 1024, 512, EP_NONE, 32};
        ga.d1 = ga.d0; ga.d2 = ga.d0; ga.s1 = 128; ga.s2 = 128;
        gemm_8p<<<dim3(128), blk512, 0, stream>>>(ga);
    }

    mix_ln<<<8192, blk, 0, stream>>>(s_prev, G, PM, WM, oln_g, oln_b, out_s);
}

// Round 9
// 519.312 us; speedup vs baseline: 1.0742x; 1.0197x over previous
//
#include <hip/hip_runtime.h>
#include <math.h>

typedef unsigned short u16;
typedef __attribute__((ext_vector_type(8))) short short8;
typedef __attribute__((ext_vector_type(4))) float f32x4;

#define AS1C(p) ((const __attribute__((address_space(1))) void*)(p))
#define AS3(p)  ((__attribute__((address_space(3))) void*)(p))

static __device__ __forceinline__ float b2f(u16 h) {
    union { unsigned u; float f; } c; c.u = ((unsigned)h) << 16; return c.f;
}
static __device__ __forceinline__ u16 f2b(float f) {
    union { float f; unsigned u; } c; c.f = f;
    unsigned r = c.u + 0x7FFFu + ((c.u >> 16) & 1u);
    return (u16)(r >> 16);
}

// Epilogue modes (runtime)
#define EP_NONE     0
#define EP_RELU     1
#define EP_SIGMOID  2
#define EP_TANH_MUL 3
#define EP_TANH_ADD 4
#define EP_DIAG     5

struct GDesc {
    const u16* A;
    const u16* W;
    const float* bias;
    const float* auxf;
    u16* outb;
    float* outf;
    int lda, ldd, N, K, ep, nbm;
};

struct GArgs { GDesc d0, d1, d2; int s1, s2; };

// 256x256 tile, BK=64, 512 threads = 8 waves. 4-phase K-tile pipeline with
// read-ahead. A-frag rows = mh*128 + wr*64 + mm*16 + (lane&15)  [mh half
// matches staged Ah half]; B-frag rows = nh*128 + wc*32 + nn*16 + (lane&15).
// Phase = [stage half(t+1)] [vmcnt(4)] [barrier] [16 MFMA on frags read one
// phase earlier] [ds_read next-needed frag set]. Staging order Ah0,Bh0,Bh1,Ah1
// makes each vmcnt(4) land exactly the half-tile the following read consumes
// (ledger: tile entry = 4 outstanding {Bh1,Ah1 of next}; each phase +2/-2).
// All ds_read addresses precomputed (8 pointers, imm offsets, K-loop
// unrolled x2 for static buffer choice) -> near-zero per-iter address VALU.
// LDS swizzle (16B slot ^= row&7) on pre-swizzled global source + swizzled
// read pointers (both sides; zero conflicts R4-R7 proven).
// REQUIRES K%64==0 and nkt even.
__global__ __launch_bounds__(512, 2)
void gemm_v2(GArgs ga)
{
    __shared__ __align__(16) u16 LDS[65536];   // buf d: A u16[d*32768,+16384) B +16384

    const int bid = (int)blockIdx.x;
    GDesc dd = (bid < ga.s1) ? ga.d0 : ((bid < ga.s2) ? ga.d1 : ga.d2);
    const int b = bid - ((bid < ga.s1) ? 0 : ((bid < ga.s2) ? ga.s1 : ga.s2));

    const int tid  = threadIdx.x;
    const int lane = tid & 63;
    const int wid  = tid >> 6;
    const int wr   = wid >> 2;          // 0..1  (64-row strip within 128-row quadrant)
    const int wc   = wid & 3;           // 0..3  (32-col strip within 128-col quadrant)

    const int bm = b % dd.nbm;
    const int bn = b / dd.nbm;
    const int lda = dd.lda, K = dd.K, N = dd.N, ldd = dd.ldd;
    const int nkt = K >> 6;

    // staging coords (pre-swizzled global source, linear LDS dest)
    const int srow  = tid >> 3;
    const int sslot = tid & 7;
    const int sgcol = (sslot ^ (srow & 7)) * 8;
    const u16* Ag = dd.A + (size_t)(bm * 256 + srow) * lda + sgcol;
    const u16* Wg = dd.W + (size_t)(bn * 256 + srow) * K + sgcol;
    const int ldst = tid * 8;

    f32x4 acc[8][4];
#pragma unroll
    for (int m = 0; m < 8; ++m)
#pragma unroll
        for (int n = 0; n < 4; ++n) acc[m][n] = (f32x4){0.f, 0.f, 0.f, 0.f};

    // ---- precomputed ds_read pointers (u16 units; frag row ≡ lane&7 mod 8)
    const int swz  = (lane & 7) << 4;           // byte XOR (bits 4-6)
    const int cnat = (lane >> 4) << 4;          // byte col base (bits 4-5)
    const int aRow = (wr * 64 + (lane & 15)) * 64;      // u16 (quadrant-local)
    const int bRow = (wc * 32 + (lane & 15)) * 64;      // u16
    const u16* pA00 = LDS + aRow + ((cnat ^ swz) >> 1);            // buf0 ks0
    const u16* pA10 = LDS + aRow + ((((64) | cnat) ^ swz) >> 1);   // buf0 ks1
    const u16* pA01 = pA00 + 32768;                                // buf1 ks0
    const u16* pA11 = pA10 + 32768;
    const u16* pB00 = LDS + 16384 + bRow + ((cnat ^ swz) >> 1);
    const u16* pB10 = LDS + 16384 + bRow + ((((64) | cnat) ^ swz) >> 1);
    const u16* pB01 = pB00 + 32768;
    const u16* pB11 = pB10 + 32768;

    short8 A0f[4][2], A1f[4][2], B0f[2][2], B1f[2][2];

    // A read: row = mh*128 + wr*64 + mm*16 + (lane&15) -> u16 off mh*8192 + mm*1024
#define READ_A(AF, PK0, PK1, MHOFF)                                              \
    {                                                                            \
        _Pragma("unroll")                                                        \
        for (int mm = 0; mm < 4; ++mm) {                                         \
            AF[mm][0] = *(const short8*)((PK0) + (MHOFF) + mm * 1024);           \
            AF[mm][1] = *(const short8*)((PK1) + (MHOFF) + mm * 1024);           \
        }                                                                        \
    }
    // B read: row = nh*128 + wc*32 + nn*16 + (lane&15) -> u16 off nh*8192 + nn*1024
#define READ_B(BF, PK0, PK1, NHOFF)                                              \
    {                                                                            \
        _Pragma("unroll")                                                        \
        for (int nn = 0; nn < 2; ++nn) {                                         \
            BF[nn][0] = *(const short8*)((PK0) + (NHOFF) + nn * 1024);           \
            BF[nn][1] = *(const short8*)((PK1) + (NHOFF) + nn * 1024);           \
        }                                                                        \
    }

#define STAGE_A(bufi, k0_, h)                                                    \
    {                                                                            \
        u16* d_ = &LDS[(bufi) * 32768 + ldst];                                   \
        _Pragma("unroll")                                                        \
        for (int j = 2 * (h); j < 2 * (h) + 2; ++j)                              \
            __builtin_amdgcn_global_load_lds(AS1C(Ag + (size_t)(j * 64) * lda + (k0_)), \
                                             AS3(d_ + j * 4096), 16, 0, 0);      \
    }
#define STAGE_B(bufi, k0_, h)                                                    \
    {                                                                            \
        u16* d_ = &LDS[(bufi) * 32768 + 16384 + ldst];                           \
        _Pragma("unroll")                                                        \
        for (int j = 2 * (h); j < 2 * (h) + 2; ++j)                              \
            __builtin_amdgcn_global_load_lds(AS1C(Wg + (size_t)(j * 64) * K + (k0_)),   \
                                             AS3(d_ + j * 4096), 16, 0, 0);      \
    }

#define VW4()                                                                    \
    {                                                                            \
        __builtin_amdgcn_sched_barrier(0);                                       \
        asm volatile("s_waitcnt vmcnt(4)" ::: "memory");                         \
        __builtin_amdgcn_sched_barrier(0);                                       \
        __builtin_amdgcn_s_barrier();                                            \
        __builtin_amdgcn_sched_barrier(0);                                       \
    }

#define QMFMA(AF, BF, mh, nh)                                                    \
    {                                                                            \
        __builtin_amdgcn_s_setprio(1);                                           \
        _Pragma("unroll")                                                        \
        for (int mm = 0; mm < 4; ++mm)                                           \
            _Pragma("unroll")                                                    \
            for (int nn = 0; nn < 2; ++nn)                                       \
                _Pragma("unroll")                                                \
                for (int ks = 0; ks < 2; ++ks)                                   \
                    acc[(mh) * 4 + mm][(nh) * 2 + nn] =                          \
                        __builtin_amdgcn_mfma_f32_16x16x32_bf16(                 \
                            AF[mm][ks], BF[nn][ks], acc[(mh) * 4 + mm][(nh) * 2 + nn], 0, 0, 0); \
        __builtin_amdgcn_s_setprio(0);                                           \
    }

    // TILE: current buf ptrs CA0/CA1/CBp0/CBp1, next buf ptrs NA0/NA1/NBp0/NBp1
#define TILE(NBUF, CA0, CA1, CBp0, CBp1, NA0, NA1, NBp0, NBp1, ktv)              \
    {                                                                            \
        const int ka_ = ((ktv) + 1 < nkt) ? (ktv) + 1 : nkt - 1;                 \
        const int k0n = ka_ << 6;                                                \
        /* ph1: q(mh0,nh0); stage Ah0(t+1); read B1(t)  [VW4 lands Bh1(t)] */    \
        STAGE_A(NBUF, k0n, 0);                                                   \
        VW4();                                                                   \
        QMFMA(A0f, B0f, 0, 0);                                                   \
        READ_B(B1f, CBp0, CBp1, 8192);                                           \
        /* ph2: q(mh0,nh1); stage Bh0(t+1); read A1(t)  [VW4 lands Ah1(t)] */    \
        STAGE_B(NBUF, k0n, 0);                                                   \
        VW4();                                                                   \
        QMFMA(A0f, B1f, 0, 1);                                                   \
        READ_A(A1f, CA0, CA1, 8192);                                             \
        /* ph3: q(mh1,nh1); stage Bh1(t+1); read A0(t+1) [VW4 lands Ah0(t+1)] */ \
        STAGE_B(NBUF, k0n, 1);                                                   \
        VW4();                                                                   \
        QMFMA(A1f, B1f, 1, 1);                                                   \
        READ_A(A0f, NA0, NA1, 0);                                                \
        /* ph4: q(mh1,nh0); stage Ah1(t+1); read B0(t+1) [VW4 lands Bh0(t+1)] */ \
        STAGE_A(NBUF, k0n, 1);                                                   \
        VW4();                                                                   \
        QMFMA(A1f, B0f, 1, 0);                                                   \
        READ_B(B0f, NBp0, NBp1, 0);                                              \
    }

    // ---- prologue: stage tile 0 in landing order Ah0,Bh0,Bh1,Ah1
    STAGE_A(0, 0, 0);
    __builtin_amdgcn_sched_barrier(0);
    STAGE_B(0, 0, 0);
    __builtin_amdgcn_sched_barrier(0);
    STAGE_B(0, 0, 1);
    __builtin_amdgcn_sched_barrier(0);
    STAGE_A(0, 0, 1);
    __builtin_amdgcn_sched_barrier(0);
    asm volatile("s_waitcnt vmcnt(4)" ::: "memory");
    __builtin_amdgcn_sched_barrier(0);
    __builtin_amdgcn_s_barrier();
    __builtin_amdgcn_sched_barrier(0);
    READ_A(A0f, pA00, pA10, 0);
    READ_B(B0f, pB00, pB10, 0);

    for (int kt = 0; kt < nkt; kt += 2) {
        TILE(1, pA00, pA10, pB00, pB10, pA01, pA11, pB01, pB11, kt);
        TILE(0, pA01, pA11, pB01, pB11, pA00, pA10, pB00, pB10, kt + 1);
    }

#undef READ_A
#undef READ_B
#undef STAGE_A
#undef STAGE_B
#undef VW4
#undef QMFMA
#undef TILE

    // epilogue: frag (m,n): R = bm*256+(m>>2)*128+wr*64+(m&3)*16+(lane>>4)*4+j
    //                       C = bn*256+(n>>1)*128+wc*32+(n&1)*16+(lane&15)
    const int ep = dd.ep;
#pragma unroll
    for (int n = 0; n < 4; ++n) {
        const int C = bn * 256 + (n >> 1) * 128 + wc * 32 + (n & 1) * 16 + (lane & 15);
        const float bv = dd.bias ? dd.bias[C] : 0.f;
#pragma unroll
        for (int m = 0; m < 8; ++m) {
            const int R0 = bm * 256 + (m >> 2) * 128 + wr * 64 + (m & 3) * 16 + ((lane >> 4) << 2);
#pragma unroll
            for (int j = 0; j < 4; ++j) {
                const int R = R0 + j;
                float v = acc[m][n][j] + bv;
                if (ep == EP_RELU)          v = fmaxf(v, 0.f);
                else if (ep == EP_SIGMOID)  v = 1.f / (1.f + expf(-v));
                else if (ep == EP_TANH_MUL) v = tanhf(v) * dd.auxf[(size_t)R * N + C];
                else if (ep == EP_TANH_ADD) v = dd.auxf[(size_t)R * N + C] + tanhf(v);
                else if (ep == EP_DIAG)     { if (R == C) v += 0.9f * tanhf(dd.auxf[R]); }
                dd.outb[(size_t)R * ldd + C] = f2b(v);
                if (dd.outf) dd.outf[(size_t)R * N + C] = v;
            }
        }
    }
}

// In-place LayerNorm over D=1024 bf16 (+optional ReLU). gam/bet fp32.
template<bool RELU>
__global__ __launch_bounds__(256)
void ln1024(u16* __restrict__ X, const float* __restrict__ gam, const float* __restrict__ bet)
{
    const int row = blockIdx.x;
    u16* xp = X + (size_t)row * 1024 + threadIdx.x * 4;
    u16 loc[4];
    *(uint2*)loc = *(const uint2*)xp;
    float x0 = b2f(loc[0]), x1 = b2f(loc[1]), x2 = b2f(loc[2]), x3 = b2f(loc[3]);
    float s = x0 + x1 + x2 + x3;
    float q = x0 * x0 + x1 * x1 + x2 * x2 + x3 * x3;
#pragma unroll
    for (int off = 32; off; off >>= 1) { s += __shfl_xor(s, off); q += __shfl_xor(q, off); }
    __shared__ float sm[8];
    const int wave = threadIdx.x >> 6, lane = threadIdx.x & 63;
    if (lane == 0) { sm[wave] = s; sm[4 + wave] = q; }
    __syncthreads();
    s = sm[0] + sm[1] + sm[2] + sm[3];
    q = sm[4] + sm[5] + sm[6] + sm[7];
    const float mean = s * (1.f / 1024.f);
    const float var  = q * (1.f / 1024.f) - mean * mean;
    const float inv  = rsqrtf(var + 1e-5f);
    const int cb = threadIdx.x * 4;
#pragma unroll
    for (int j = 0; j < 4; ++j) {
        float y = (b2f(loc[j]) - mean) * inv * gam[cb + j] + bet[cb + j];
        if (RELU) y = fmaxf(y, 0.f);
        loc[j] = f2b(y);
    }
    *(uint2*)xp = *(uint2*)loc;
}

// s_t = LN(s_prev + g*pm + (1-g)*wm) over D=1024. sp fp32, g/pm/wm bf16, out fp32.
__global__ __launch_bounds__(256)
void mix_ln(const float* __restrict__ sp, const u16* __restrict__ gt,
            const u16* __restrict__ pm, const u16* __restrict__ wm,
            const float* __restrict__ og, const float* __restrict__ ob,
            float* __restrict__ out)
{
    const int row = blockIdx.x;
    const size_t base = (size_t)row * 1024 + threadIdx.x * 4;
    float4 lsp = *(const float4*)(sp + base);
    u16 lg[4], lp[4], lw[4];
    *(uint2*)lg = *(const uint2*)(gt + base);
    *(uint2*)lp = *(const uint2*)(pm + base);
    *(uint2*)lw = *(const uint2*)(wm + base);
    float x[4];
    const float* lspp = (const float*)&lsp;
#pragma unroll
    for (int j = 0; j < 4; ++j) {
        float g = b2f(lg[j]);
        x[j] = lspp[j] + g * b2f(lp[j]) + (1.f - g) * b2f(lw[j]);
    }
    float s = x[0] + x[1] + x[2] + x[3];
    float q = x[0]*x[0] + x[1]*x[1] + x[2]*x[2] + x[3]*x[3];
#pragma unroll
    for (int off = 32; off; off >>= 1) { s += __shfl_xor(s, off); q += __shfl_xor(q, off); }
    __shared__ float sm[8];
    const int wave = threadIdx.x >> 6, lane = threadIdx.x & 63;
    if (lane == 0) { sm[wave] = s; sm[4 + wave] = q; }
    __syncthreads();
    s = sm[0] + sm[1] + sm[2] + sm[3];
    q = sm[4] + sm[5] + sm[6] + sm[7];
    const float mean = s * (1.f / 1024.f);
    const float var  = q * (1.f / 1024.f) - mean * mean;
    const float inv  = rsqrtf(var + 1e-5f);
    const int cb = threadIdx.x * 4;
    float4 o;
    float* op = (float*)&o;
#pragma unroll
    for (int j = 0; j < 4; ++j)
        op[j] = (x[j] - mean) * inv * og[cb + j] + ob[cb + j];
    *(float4*)(out + base) = o;
}

// Batched strided copy/convert: fp32->bf16 or bf16->bf16, 8 elems/thread.
struct CDesc { const void* src; u16* dst; int srcCols8; int dstStride; int dstOff; unsigned end; int isbf16; };
struct CArgs { CDesc d[16]; unsigned total; };

__global__ __launch_bounds__(256)
void multi_copy(CArgs ca)
{
    const unsigned idx = blockIdx.x * 256 + threadIdx.x;
    if (idx >= ca.total) return;
    int i = 0; unsigned start = 0;
    while (idx >= ca.d[i].end) { start = ca.d[i].end; ++i; }
    const CDesc cd = ca.d[i];
    const unsigned local = idx - start;
    const int r = local / cd.srcCols8;
    const int c = local % cd.srcCols8;
    u16 o[8];
    if (cd.isbf16) {
        *(uint4*)o = *(const uint4*)((const u16*)cd.src + ((size_t)r * cd.srcCols8 + c) * 8);
    } else {
        const float* s = (const float*)cd.src + ((size_t)r * cd.srcCols8 + c) * 8;
        const float4 a = *(const float4*)s;
        const float4 bq = *(const float4*)(s + 4);
        const float* ap = (const float*)&a;
        const float* bp = (const float*)&bq;
#pragma unroll
        for (int j = 0; j < 4; ++j) { o[j] = f2b(ap[j]); o[4 + j] = f2b(bp[j]); }
    }
    *(uint4*)(cd.dst + (size_t)r * cd.dstStride + cd.dstOff + (size_t)c * 8) = *(uint4*)o;
}

extern "C" void kernel_launch(void* const* d_in, const int* in_sizes, int n_in,
                              void* d_out, int out_size, void* d_ws, size_t ws_size,
                              hipStream_t stream)
{
    const float* s_prev = (const float*)d_in[0];
    const float* w_prev = (const float*)d_in[1];
    const float* p_prev = (const float*)d_in[2];
    const float* e_t    = (const float*)d_in[3];
    const float* c_t    = (const float*)d_in[4];
    const float* fw1    = (const float*)d_in[5];
    const float* fb1    = (const float*)d_in[6];
    const float* fln_g  = (const float*)d_in[7];
    const float* fln_b  = (const float*)d_in[8];
    const float* fw2    = (const float*)d_in[9];
    const float* fb2    = (const float*)d_in[10];
    const float* A_diag = (const float*)d_in[11];
    const float* A_U    = (const float*)d_in[12];
    const float* A_V    = (const float*)d_in[13];
    const float* amod_w = (const float*)d_in[14];
    const float* amod_b = (const float*)d_in[15];
    const float* bnet_w = (const float*)d_in[16];
    const float* bnet_b = (const float*)d_in[17];
    const float* pw1    = (const float*)d_in[18];
    const float* pb1    = (const float*)d_in[19];
    const float* pln_g  = (const float*)d_in[20];
    const float* pln_b  = (const float*)d_in[21];
    const float* pw2    = (const float*)d_in[22];
    const float* pb2    = (const float*)d_in[23];
    const float* pw3    = (const float*)d_in[24];
    const float* pb3    = (const float*)d_in[25];
    const float* gw     = (const float*)d_in[26];
    const float* gb     = (const float*)d_in[27];
    const float* uw     = (const float*)d_in[28];
    const float* up     = (const float*)d_in[29];
    const float* oln_g  = (const float*)d_in[30];
    const float* oln_b  = (const float*)d_in[31];

    float* out_s = (float*)d_out;
    float* out_w = out_s + (size_t)8192 * 1024;
    float* out_p = out_w + (size_t)8192 * 1024;

    u16* ws = (u16*)d_ws;
    u16* FIN  = ws;
    u16* W_bf = ws + 12582912;
    u16* H    = ws + 20971520;
    u16* P_bf = H;
    u16* Z    = ws + 29360128;
    u16* G    = ws + 33554432;
    u16* ACAT = ws + 41943040;
    u16* PM   = ACAT;
    u16* WM   = ACAT + 8388608;
    u16* WCAT = ws + 58720256;
    u16* wb   = ws + 60817408;
    u16* fw1b  = wb;
    u16* gwb   = wb + 2621440;
    u16* fw2b  = wb + 5242880;
    u16* amodb = wb + 5767168;
    u16* pw1b  = wb + 6291456;
    u16* pw2b  = wb + 7864320;
    u16* pw3b  = wb + 8388608;
    u16* uwb   = wb + 8650752;
    u16* upb   = wb + 9699328;
    u16* AUb   = wb + 10223616;
    u16* AVb   = wb + 10485760;

    const dim3 blk(256);
    const dim3 blk512(512);

    // ---------- batch 1
    {
        CArgs ca; unsigned cum = 0; int nd = 0;
        auto push = [&](const void* src, u16* dst, int cols8, int stride, int off,
                        int rows, int isbf) {
            cum += (unsigned)rows * cols8;
            ca.d[nd++] = CDesc{src, dst, cols8, stride, off, cum, isbf};
        };
        push(fw1,    fw1b,  320, 2560, 0,    1024, 0);
        push(gw,     gwb,   320, 2560, 0,    1024, 0);
        push(fw2,    fw2b,  128, 1024, 0,    512,  0);
        push(amod_w, amodb, 64,  512,  0,    1024, 0);
        push(pw1,    pw1b,  192, 1536, 0,    1024, 0);
        push(pw2,    pw2b,  128, 1024, 0,    512,  0);
        push(pw3,    pw3b,  64,  512,  0,    512,  0);
        push(uw,     uwb,   128, 1024, 0,    1024, 0);
        push(up,     upb,   64,  512,  0,    1024, 0);
        push(A_U,    AUb,   32,  256,  0,    1024, 0);
        push(A_V,    AVb,   32,  256,  0,    1024, 0);
        push(s_prev, FIN,   128, 2560, 0,    8192, 0);
        push(e_t,    FIN,   128, 2560, 1024, 8192, 0);
        push(c_t,    FIN,   64,  2560, 2048, 8192, 0);
        push(c_t,    ACAT,  64,  2048, 1024, 8192, 0);
        push(bnet_w, WCAT,  128, 2048, 1024, 1024, 0);
        ca.total = cum;
        multi_copy<<<dim3((cum + 255) / 256), blk, 0, stream>>>(ca);
    }

    // ---------- fused GEMM 1: fw1 (H) || gate (G) -> 256 blocks
    {
        GArgs ga;
        ga.d0 = GDesc{FIN, fw1b, fb1, nullptr, H, nullptr, 2560, 1024, 1024, 2560, EP_NONE,    32};
        ga.d1 = GDesc{FIN, gwb,  gb,  nullptr, G, nullptr, 2560, 1024, 1024, 2560, EP_SIGMOID, 32};
        ga.d2 = ga.d1; ga.s1 = 128; ga.s2 = 256;
        gemm_v2<<<dim3(256), blk512, 0, stream>>>(ga);
    }
    ln1024<true><<<8192, blk, 0, stream>>>(H, fln_g, fln_b);

    // ---------- fused GEMM 2: fw2 (Z) || amod (ACAT) || A_base (WCAT) -> 208 blocks
    {
        GArgs ga;
        ga.d0 = GDesc{H,          fw2b,  fb2,     nullptr, Z,    nullptr, 1024, 512,  512,  1024, EP_NONE,     32};
        ga.d1 = GDesc{FIN + 2048, amodb, amod_b,  w_prev,  ACAT, nullptr, 2560, 2048, 1024, 512,  EP_TANH_MUL, 32};
        ga.d2 = GDesc{AUb,        AVb,   nullptr, A_diag,  WCAT, nullptr, 256,  2048, 1024, 256,  EP_DIAG,     4};
        ga.s1 = 64; ga.s2 = 192;
        gemm_v2<<<dim3(208), blk512, 0, stream>>>(ga);
    }

    // ---------- batch 2
    {
        CArgs ca; unsigned cum = 0; int nd = 0;
        auto push = [&](const void* src, u16* dst, int cols8, int stride, int off,
                        int rows, int isbf) {
            cum += (unsigned)rows * cols8;
            ca.d[nd++] = CDesc{src, dst, cols8, stride, off, cum, isbf};
        };
        push(p_prev, FIN,  64, 1536, 0,    8192, 0);
        push(Z,      FIN,  64, 1536, 512,  8192, 1);
        push(c_t,    FIN,  64, 1536, 1024, 8192, 0);
        push(Z,      ACAT, 64, 2048, 1536, 8192, 1);
        ca.total = cum;
        multi_copy<<<dim3((cum + 255) / 256), blk, 0, stream>>>(ca);
    }

    // ---------- fused GEMM 3: w_t (ACAT@WCAT^T) || pw1 (PIN) -> 256 blocks
    {
        GArgs ga;
        ga.d0 = GDesc{ACAT, WCAT, bnet_b, nullptr, W_bf, out_w,   2048, 1024, 1024, 2048, EP_NONE, 32};
        ga.d1 = GDesc{FIN,  pw1b, pb1,    nullptr, H,    nullptr, 1536, 1024, 1024, 1536, EP_NONE, 32};
        ga.d2 = ga.d1; ga.s1 = 128; ga.s2 = 256;
        gemm_v2<<<dim3(256), blk512, 0, stream>>>(ga);
    }
    ln1024<true><<<8192, blk, 0, stream>>>(H, pln_g, pln_b);

    // ---------- fused GEMM 4: pw2 (H -> Z, relu) || uw (W_bf -> WM) -> 192 blocks
    {
        GArgs ga;
        ga.d0 = GDesc{H,    pw2b, pb2,     nullptr, Z,  nullptr, 1024, 512,  512,  1024, EP_RELU, 32};
        ga.d1 = GDesc{W_bf, uwb,  nullptr, nullptr, WM, nullptr, 1024, 1024, 1024, 1024, EP_NONE, 32};
        ga.d2 = ga.d1; ga.s1 = 64; ga.s2 = 192;
        gemm_v2<<<dim3(192), blk512, 0, stream>>>(ga);
    }

    // ---------- pw3
    {
        GArgs ga;
        ga.d0 = GDesc{Z, pw3b, pb3, p_prev, P_bf, out_p, 512, 512, 512, 512, EP_TANH_ADD, 32};
        ga.d1 = ga.d0; ga.d2 = ga.d0; ga.s1 = 64; ga.s2 = 64;
        gemm_v2<<<dim3(64), blk512, 0, stream>>>(ga);
    }

    // ---------- up
    {
        GArgs ga;
        ga.d0 = GDesc{P_bf, upb, nullptr, nullptr, PM, nullptr, 512, 1024, 1024, 512, EP_NONE, 32};
        ga.d1 = ga.d0; ga.d2 = ga.d0; ga.s1 = 128; ga.s2 = 128;
        gemm_v2<<<dim3(128), blk512, 0, stream>>>(ga);
    }

    mix_ln<<<8192, blk, 0, stream>>>(s_prev, G, PM, WM, oln_g, oln_b, out_s);
}